// Round 1
// baseline (1129.509 us; speedup 1.0000x reference)
//
#include <hip/hip_runtime.h>

// Problem constants (B,C,H,W)=(4,128,64,64), N=H*W=4096, GROUPS=8
constexpr int B_ = 4;
constexpr int C_ = 128;
constexpr int N_ = 4096;
constexpr int G_ = 8;
constexpr int CperG = 16;            // C_/G_
constexpr float EPS_ = 1e-5f;
constexpr float SCALE_ = 0.08838834764831845f;  // 1/sqrt(C)

// ---------------- 1. GroupNorm statistics: one block per (b,g) ----------------
__global__ __launch_bounds__(256) void gn_stats_kernel(const float* __restrict__ x,
                                                       float* __restrict__ stats) {
    int bg = blockIdx.x;  // b*G + g ; channels are contiguous per group
    const float4* xp4 = (const float4*)(x + (size_t)bg * (CperG * N_));
    const int n4 = CperG * N_ / 4;  // 16384 float4
    float s = 0.f, ss = 0.f;
    for (int idx = threadIdx.x; idx < n4; idx += 256) {
        float4 v = xp4[idx];
        s  += v.x + v.y + v.z + v.w;
        ss += v.x*v.x + v.y*v.y + v.z*v.z + v.w*v.w;
    }
    #pragma unroll
    for (int off = 32; off > 0; off >>= 1) {
        s  += __shfl_down(s, off);
        ss += __shfl_down(ss, off);
    }
    __shared__ float rs[4], rss[4];
    int wave = threadIdx.x >> 6, lane = threadIdx.x & 63;
    if (lane == 0) { rs[wave] = s; rss[wave] = ss; }
    __syncthreads();
    if (threadIdx.x == 0) {
        float S  = rs[0] + rs[1] + rs[2] + rs[3];
        float SS = rss[0] + rss[1] + rss[2] + rss[3];
        float inv = 1.f / (float)(CperG * N_);
        float mean = S * inv;
        float var  = SS * inv - mean * mean;   // biased var, matches jnp.var
        stats[bg*2]     = mean;
        stats[bg*2 + 1] = rsqrtf(var + EPS_);
    }
}

// ---------------- 2. QKV GEMM with fused GroupNorm apply ----------------
// qkv[b][o][n] = sum_c qkv_w[o][c] * h[b][c][n] + qkv_b[o],
// h = (x-mean)*rstd*nw + nb computed on the fly while staging the tile.
constexpr int NT = 64;  // pixel tile
constexpr int OT = 64;  // output-channel tile

__global__ __launch_bounds__(256) void qkv_gemm_kernel(const float* __restrict__ x,
                                                       const float* __restrict__ stats,
                                                       const float* __restrict__ nw,
                                                       const float* __restrict__ nb,
                                                       const float* __restrict__ qw,
                                                       const float* __restrict__ qb,
                                                       float* __restrict__ qkv) {
    int n0 = blockIdx.x * NT;
    int o0 = blockIdx.y * OT;
    int b  = blockIdx.z;
    __shared__ float hs[C_ * NT];   // [c][n]  32 KB
    __shared__ float ws[OT * C_];   // [o][c]  32 KB
    int t = threadIdx.x;
    // stage normalized h tile: 2048 float4
    #pragma unroll
    for (int r = 0; r < 8; ++r) {
        int idx = t + (r << 8);
        int c  = idx >> 4;
        int nl = (idx & 15) << 2;
        int g  = c >> 4;
        float mean = stats[(b*G_ + g)*2];
        float rstd = stats[(b*G_ + g)*2 + 1];
        float w = nw[c], bias = nb[c];
        float4 xv = *(const float4*)(x + ((size_t)(b*C_ + c))*N_ + n0 + nl);
        float4 h;
        h.x = (xv.x - mean)*rstd*w + bias;
        h.y = (xv.y - mean)*rstd*w + bias;
        h.z = (xv.z - mean)*rstd*w + bias;
        h.w = (xv.w - mean)*rstd*w + bias;
        *(float4*)(hs + c*NT + nl) = h;
    }
    // stage weight tile: 2048 float4
    #pragma unroll
    for (int r = 0; r < 8; ++r) {
        int idx = t + (r << 8);
        int o  = idx >> 5;
        int cc = (idx & 31) << 2;
        *(float4*)(ws + o*C_ + cc) = *(const float4*)(qw + (size_t)(o0 + o)*C_ + cc);
    }
    __syncthreads();
    // 4x4 register tile per thread; K=128 in one pass (no k-loop reload)
    int tn = (t & 15) << 2;
    int to = (t >> 4) << 2;
    float acc[4][4];
    #pragma unroll
    for (int a = 0; a < 4; ++a)
        #pragma unroll
        for (int n = 0; n < 4; ++n) acc[a][n] = 0.f;
    for (int c4 = 0; c4 < C_; c4 += 4) {
        float hrow[4][4];
        #pragma unroll
        for (int cc2 = 0; cc2 < 4; ++cc2) {
            float4 h4 = *(float4*)(hs + (c4 + cc2)*NT + tn);
            hrow[cc2][0] = h4.x; hrow[cc2][1] = h4.y;
            hrow[cc2][2] = h4.z; hrow[cc2][3] = h4.w;
        }
        #pragma unroll
        for (int a = 0; a < 4; ++a) {
            float4 w4 = *(float4*)(ws + (to + a)*C_ + c4);
            float wr[4] = {w4.x, w4.y, w4.z, w4.w};
            #pragma unroll
            for (int cc2 = 0; cc2 < 4; ++cc2)
                #pragma unroll
                for (int n = 0; n < 4; ++n)
                    acc[a][n] += wr[cc2] * hrow[cc2][n];
        }
    }
    #pragma unroll
    for (int a = 0; a < 4; ++a) {
        int o = o0 + to + a;
        float bias = qb[o];
        float4 res;
        res.x = acc[a][0] + bias; res.y = acc[a][1] + bias;
        res.z = acc[a][2] + bias; res.w = acc[a][3] + bias;
        *(float4*)(qkv + ((size_t)b*(3*C_) + o)*N_ + n0 + tn) = res;
    }
}

// ---------------- 3. Flash attention + fused proj + residual ----------------
// One block per (b, 32-query tile). Online softmax over 4096 keys in 32-col
// LDS tiles. Epilogue: proj (C x C) + proj_b + residual, no HBM round-trip
// for the attention output.
constexpr int TI = 32;
constexpr int TJ = 32;

__global__ __launch_bounds__(256) void attn_kernel(const float* __restrict__ qkv,
                                                   const float* __restrict__ x,
                                                   const float* __restrict__ pw,
                                                   const float* __restrict__ pb,
                                                   float* __restrict__ out) {
    int b  = blockIdx.y;
    int i0 = blockIdx.x * TI;
    const float* qf = qkv + (size_t)b * 3 * C_ * N_;
    const float* kf = qf + (size_t)C_ * N_;
    const float* vf = qf + (size_t)2 * C_ * N_;

    __shared__ float smem[C_*TI + 2*C_*TJ];  // qs | ks | vs  (48 KB)
    float* qs = smem;
    float* ks = smem + C_*TI;
    float* vs = ks + C_*TJ;
    __shared__ float Ss[TI * 36];            // padded [32][36]
    __shared__ float sm[TI], sl[TI], sa[TI];

    int t = threadIdx.x;
    // stage Q tile [c][i]
    #pragma unroll
    for (int r = 0; r < 4; ++r) {
        int idx = t + (r << 8);
        int c  = idx >> 3;
        int il = (idx & 7) << 2;
        *(float4*)(qs + c*TI + il) = *(const float4*)(qf + (size_t)c*N_ + i0 + il);
    }
    if (t < TI) { sm[t] = -1e30f; sl[t] = 0.f; }

    int ti = t & 31;      // query index this thread accumulates for
    int cg = t >> 5;      // channel group (16 channels each)
    float acc[16];
    #pragma unroll
    for (int k = 0; k < 16; ++k) acc[k] = 0.f;

    int i2 = (t & 15) << 1;   // S-tile: 2i x 2j per thread
    int j2 = (t >> 4) << 1;

    for (int j0 = 0; j0 < N_; j0 += TJ) {
        __syncthreads();  // prev PV done before overwriting ks/vs (and Q visible, iter 0)
        #pragma unroll
        for (int r = 0; r < 4; ++r) {
            int idx = t + (r << 8);
            int c  = idx >> 3;
            int jl = (idx & 7) << 2;
            *(float4*)(ks + c*TJ + jl) = *(const float4*)(kf + (size_t)c*N_ + j0 + jl);
            *(float4*)(vs + c*TJ + jl) = *(const float4*)(vf + (size_t)c*N_ + j0 + jl);
        }
        __syncthreads();
        // S = (Q^T K) * scale
        float s00 = 0.f, s01 = 0.f, s10 = 0.f, s11 = 0.f;
        for (int c = 0; c < C_; ++c) {
            float q0 = qs[c*TI + i2], q1 = qs[c*TI + i2 + 1];
            float k0 = ks[c*TJ + j2], k1 = ks[c*TJ + j2 + 1];
            s00 += q0*k0; s01 += q0*k1; s10 += q1*k0; s11 += q1*k1;
        }
        Ss[i2*36 + j2]         = s00 * SCALE_;
        Ss[i2*36 + j2 + 1]     = s01 * SCALE_;
        Ss[(i2+1)*36 + j2]     = s10 * SCALE_;
        Ss[(i2+1)*36 + j2 + 1] = s11 * SCALE_;
        __syncthreads();
        // online softmax, one thread per query row
        if (t < TI) {
            float m_old = sm[t];
            float rmax = m_old;
            for (int j = 0; j < TJ; ++j) rmax = fmaxf(rmax, Ss[t*36 + j]);
            float alpha = __expf(m_old - rmax);
            float sum = 0.f;
            for (int j = 0; j < TJ; ++j) {
                float p = __expf(Ss[t*36 + j] - rmax);
                Ss[t*36 + j] = p;
                sum += p;
            }
            sm[t] = rmax;
            sl[t] = sl[t] * alpha + sum;
            sa[t] = alpha;
        }
        __syncthreads();
        // rescale + accumulate P*V
        float al = sa[ti];
        #pragma unroll
        for (int k = 0; k < 16; ++k) acc[k] *= al;
        #pragma unroll
        for (int jq = 0; jq < TJ/4; ++jq) {
            float4 p4 = *(float4*)(Ss + ti*36 + (jq << 2));
            #pragma unroll
            for (int k = 0; k < 16; ++k) {
                float4 v4 = *(float4*)(vs + (cg*16 + k)*TJ + (jq << 2));
                acc[k] += p4.x*v4.x + p4.y*v4.y + p4.z*v4.z + p4.w*v4.w;
            }
        }
    }
    __syncthreads();
    // normalize, park attention output transposed in LDS (reuse ks/vs space)
    float* outs = ks;  // needs 32*132 = 4224 floats < 8192 available
    float linv = 1.f / sl[ti];
    #pragma unroll
    for (int k = 0; k < 16; ++k) outs[ti*132 + cg*16 + k] = acc[k] * linv;
    __syncthreads();
    // proj + bias + residual
    float po[16];
    #pragma unroll
    for (int k = 0; k < 16; ++k) po[k] = 0.f;
    for (int cq = 0; cq < C_; cq += 4) {
        float4 h4 = *(float4*)(outs + ti*132 + cq);
        #pragma unroll
        for (int k = 0; k < 16; ++k) {
            const float4 w4 = *(const float4*)(pw + (size_t)(cg*16 + k)*C_ + cq);
            po[k] += w4.x*h4.x + w4.y*h4.y + w4.z*h4.z + w4.w*h4.w;
        }
    }
    #pragma unroll
    for (int k = 0; k < 16; ++k) {
        int o = cg*16 + k;
        size_t off = ((size_t)b*C_ + o)*N_ + i0 + ti;
        out[off] = x[off] + po[k] + pb[o];
    }
}

extern "C" void kernel_launch(void* const* d_in, const int* in_sizes, int n_in,
                              void* d_out, int out_size, void* d_ws, size_t ws_size,
                              hipStream_t stream) {
    const float* x  = (const float*)d_in[0];
    const float* nw = (const float*)d_in[1];
    const float* nb = (const float*)d_in[2];
    const float* qw = (const float*)d_in[3];
    const float* qb = (const float*)d_in[4];
    const float* pw = (const float*)d_in[5];
    const float* pb = (const float*)d_in[6];
    float* out = (float*)d_out;

    // workspace layout: [stats: 64 floats][qkv: B*3C*N floats = 25.2 MB]
    float* stats = (float*)d_ws;
    float* qkv   = stats + 64;   // 256 B offset keeps float4 alignment

    gn_stats_kernel<<<dim3(B_*G_), 256, 0, stream>>>(x, stats);
    qkv_gemm_kernel<<<dim3(N_/NT, (3*C_)/OT, B_), 256, 0, stream>>>(
        x, stats, nw, nb, qw, qb, qkv);
    attn_kernel<<<dim3(N_/TI, B_), 256, 0, stream>>>(qkv, x, pw, pb, out);
}

// Round 2
// 272.776 us; speedup vs baseline: 4.1408x; 4.1408x over previous
//
#include <hip/hip_runtime.h>

typedef float  f32x4  __attribute__((ext_vector_type(4)));
typedef short  bf16x8 __attribute__((ext_vector_type(8)));
typedef unsigned short u16;

constexpr int B_ = 4;
constexpr int C_ = 128;
constexpr int N_ = 4096;
constexpr int G_ = 8;
constexpr int CperG = 16;
constexpr float EPS_ = 1e-5f;
constexpr float SCALE_ = 0.08838834764831845f;  // 1/sqrt(C)

__device__ inline u16 f2bf(float f) {
    union { float f; unsigned u; } v; v.f = f;
    unsigned r = v.u + 0x7fffu + ((v.u >> 16) & 1u);  // RNE
    return (u16)(r >> 16);
}

// ---------------- 1. GroupNorm statistics ----------------
__global__ __launch_bounds__(256) void gn_stats_kernel(const float* __restrict__ x,
                                                       float* __restrict__ stats) {
    int bg = blockIdx.x;
    const float4* xp4 = (const float4*)(x + (size_t)bg * (CperG * N_));
    const int n4 = CperG * N_ / 4;
    float s = 0.f, ss = 0.f;
    for (int idx = threadIdx.x; idx < n4; idx += 256) {
        float4 v = xp4[idx];
        s  += v.x + v.y + v.z + v.w;
        ss += v.x*v.x + v.y*v.y + v.z*v.z + v.w*v.w;
    }
    #pragma unroll
    for (int off = 32; off > 0; off >>= 1) {
        s  += __shfl_down(s, off);
        ss += __shfl_down(ss, off);
    }
    __shared__ float rs[4], rss[4];
    int wave = threadIdx.x >> 6, lane = threadIdx.x & 63;
    if (lane == 0) { rs[wave] = s; rss[wave] = ss; }
    __syncthreads();
    if (threadIdx.x == 0) {
        float S  = rs[0] + rs[1] + rs[2] + rs[3];
        float SS = rss[0] + rss[1] + rss[2] + rss[3];
        float inv = 1.f / (float)(CperG * N_);
        float mean = S * inv;
        float var  = SS * inv - mean * mean;
        stats[bg*2]     = mean;
        stats[bg*2 + 1] = rsqrtf(var + EPS_);
    }
}

// ---------------- 1b. pw fp32 -> bf16 ----------------
__global__ __launch_bounds__(256) void cvt_pw_kernel(const float* __restrict__ pw,
                                                     u16* __restrict__ pwbf) {
    int i = (blockIdx.x * 256 + threadIdx.x) * 4;   // 16384 elems, grid 16
    float4 v = *(const float4*)(pw + i);
    ushort4 o;
    o.x = f2bf(v.x); o.y = f2bf(v.y); o.z = f2bf(v.z); o.w = f2bf(v.w);
    *(ushort4*)(pwbf + i) = o;
}

// ---------------- 2. QKV GEMM (fused GN) -> bf16 mfma-friendly layouts --------
// Qt[b][n][c] = (q + qb) * SCALE   (bf16, transposed)
// Kt[b][n][c] = (k + qb)           (bf16, transposed)
// Vb[b][c][n] = (v + qb)           (bf16, natural)
constexpr int NT = 64;
constexpr int OT = 64;

__global__ __launch_bounds__(256) void qkv_gemm_kernel(const float* __restrict__ x,
                                                       const float* __restrict__ stats,
                                                       const float* __restrict__ nw,
                                                       const float* __restrict__ nb,
                                                       const float* __restrict__ qw,
                                                       const float* __restrict__ qb,
                                                       u16* __restrict__ Qt,
                                                       u16* __restrict__ Kt,
                                                       u16* __restrict__ Vb) {
    int n0 = blockIdx.x * NT;
    int o0 = blockIdx.y * OT;
    int b  = blockIdx.z;
    __shared__ float hs[C_ * NT];
    __shared__ float ws[OT * C_];
    int t = threadIdx.x;
    #pragma unroll
    for (int r = 0; r < 8; ++r) {
        int idx = t + (r << 8);
        int c  = idx >> 4;
        int nl = (idx & 15) << 2;
        int g  = c >> 4;
        float mean = stats[(b*G_ + g)*2];
        float rstd = stats[(b*G_ + g)*2 + 1];
        float w = nw[c], bias = nb[c];
        float4 xv = *(const float4*)(x + ((size_t)(b*C_ + c))*N_ + n0 + nl);
        float4 h;
        h.x = (xv.x - mean)*rstd*w + bias;
        h.y = (xv.y - mean)*rstd*w + bias;
        h.z = (xv.z - mean)*rstd*w + bias;
        h.w = (xv.w - mean)*rstd*w + bias;
        *(float4*)(hs + c*NT + nl) = h;
    }
    #pragma unroll
    for (int r = 0; r < 8; ++r) {
        int idx = t + (r << 8);
        int o  = idx >> 5;
        int cc = (idx & 31) << 2;
        *(float4*)(ws + o*C_ + cc) = *(const float4*)(qw + (size_t)(o0 + o)*C_ + cc);
    }
    __syncthreads();
    int tn = (t & 15) << 2;
    int to = (t >> 4) << 2;
    float acc[4][4];
    #pragma unroll
    for (int a = 0; a < 4; ++a)
        #pragma unroll
        for (int n = 0; n < 4; ++n) acc[a][n] = 0.f;
    for (int c4 = 0; c4 < C_; c4 += 4) {
        float hrow[4][4];
        #pragma unroll
        for (int cc2 = 0; cc2 < 4; ++cc2) {
            float4 h4 = *(float4*)(hs + (c4 + cc2)*NT + tn);
            hrow[cc2][0] = h4.x; hrow[cc2][1] = h4.y;
            hrow[cc2][2] = h4.z; hrow[cc2][3] = h4.w;
        }
        #pragma unroll
        for (int a = 0; a < 4; ++a) {
            float4 w4 = *(float4*)(ws + (to + a)*C_ + c4);
            float wr[4] = {w4.x, w4.y, w4.z, w4.w};
            #pragma unroll
            for (int cc2 = 0; cc2 < 4; ++cc2)
                #pragma unroll
                for (int n = 0; n < 4; ++n)
                    acc[a][n] += wr[cc2] * hrow[cc2][n];
        }
    }
    float bias[4];
    #pragma unroll
    for (int a = 0; a < 4; ++a) bias[a] = qb[o0 + to + a];

    if (o0 < C_) {              // Q: Qt[b][n][c], scaled
        #pragma unroll
        for (int nn = 0; nn < 4; ++nn) {
            ushort4 q4;
            q4.x = f2bf((acc[0][nn] + bias[0]) * SCALE_);
            q4.y = f2bf((acc[1][nn] + bias[1]) * SCALE_);
            q4.z = f2bf((acc[2][nn] + bias[2]) * SCALE_);
            q4.w = f2bf((acc[3][nn] + bias[3]) * SCALE_);
            *(ushort4*)(Qt + ((size_t)b*N_ + n0 + tn + nn)*C_ + o0 + to) = q4;
        }
    } else if (o0 < 2*C_) {     // K: Kt[b][n][c]
        #pragma unroll
        for (int nn = 0; nn < 4; ++nn) {
            ushort4 k4;
            k4.x = f2bf(acc[0][nn] + bias[0]);
            k4.y = f2bf(acc[1][nn] + bias[1]);
            k4.z = f2bf(acc[2][nn] + bias[2]);
            k4.w = f2bf(acc[3][nn] + bias[3]);
            *(ushort4*)(Kt + ((size_t)b*N_ + n0 + tn + nn)*C_ + (o0 - C_) + to) = k4;
        }
    } else {                    // V: Vb[b][c][n]
        #pragma unroll
        for (int a = 0; a < 4; ++a) {
            ushort4 v4;
            v4.x = f2bf(acc[a][0] + bias[a]);
            v4.y = f2bf(acc[a][1] + bias[a]);
            v4.z = f2bf(acc[a][2] + bias[a]);
            v4.w = f2bf(acc[a][3] + bias[a]);
            *(ushort4*)(Vb + ((size_t)b*C_ + (o0 - 2*C_) + to + a)*N_ + n0 + tn) = v4;
        }
    }
}

// ---------------- 3. MFMA flash attention + mfma proj + residual ----------------
// Block: 32 queries, 4 waves. Per iter: 128 keys.
// S^T = K.Q^T via mfma (A=K direct from global, B=Q persistent regs).
// Softmax in regs + LDS partials. P -> LDS [qrow][key] bf16 (A-layout for PV).
// PV: B=V direct from global. Epilogue: proj via mfma (B=pw bf16 direct).
constexpr int PSTR = 136;   // P row stride (bf16): 16B-aligned, stride/4 odd -> bank-balanced

__global__ __launch_bounds__(256, 2) void attn_kernel(const u16* __restrict__ Qt,
                                                      const u16* __restrict__ Kt,
                                                      const u16* __restrict__ Vb,
                                                      const u16* __restrict__ pwbf,
                                                      const float* __restrict__ pb,
                                                      const float* __restrict__ x,
                                                      float* __restrict__ out) {
    int lb = blockIdx.x;
    int b  = lb & 3;                                   // XCD-swizzle: L2 keeps 1 batch/XCD
    int i0 = 32 * ((lb >> 3) + ((lb & 4) ? 64 : 0));
    int t = threadIdx.x;
    int w = t >> 6;
    int lane = t & 63;
    int lo = lane & 15;
    int hi = lane >> 4;

    const u16* Qb = Qt + (size_t)b * N_ * C_;
    const u16* Kb = Kt + (size_t)b * N_ * C_;
    const u16* Vv = Vb + (size_t)b * C_ * N_;

    __shared__ u16 Ps[32 * PSTR];                      // P round-trip; reused as att
    __shared__ __align__(16) float pm[32][4];
    __shared__ __align__(16) float pl[32][4];
    __shared__ __align__(16) float alphaS[32];
    __shared__ __align__(16) float linvS[32];

    // persistent Q B-frags: [qt][chunk]
    bf16x8 qf[2][4];
    #pragma unroll
    for (int qt = 0; qt < 2; ++qt)
        #pragma unroll
        for (int ch = 0; ch < 4; ++ch)
            qf[qt][ch] = *(const bf16x8*)(Qb + (size_t)(i0 + 16*qt + lo)*C_ + 32*ch + 8*hi);

    f32x4 acc_o[2][2];
    #pragma unroll
    for (int qt = 0; qt < 2; ++qt)
        #pragma unroll
        for (int ct = 0; ct < 2; ++ct)
            acc_o[qt][ct] = (f32x4){0.f, 0.f, 0.f, 0.f};
    float m_old[2] = {-3e38f, -3e38f};
    float l_run[2] = {0.f, 0.f};

    for (int j0 = 0; j0 < N_; j0 += 128) {
        // ---- QK: S^T frags [kt][qt], keys 32w+16kt, qrows 16qt ----
        f32x4 s[2][2];
        #pragma unroll
        for (int kt = 0; kt < 2; ++kt)
            #pragma unroll
            for (int qt = 0; qt < 2; ++qt)
                s[kt][qt] = (f32x4){0.f, 0.f, 0.f, 0.f};
        #pragma unroll
        for (int ch = 0; ch < 4; ++ch) {
            bf16x8 kf0 = *(const bf16x8*)(Kb + (size_t)(j0 + 32*w + lo)*C_      + 32*ch + 8*hi);
            bf16x8 kf1 = *(const bf16x8*)(Kb + (size_t)(j0 + 32*w + 16 + lo)*C_ + 32*ch + 8*hi);
            s[0][0] = __builtin_amdgcn_mfma_f32_16x16x32_bf16(kf0, qf[0][ch], s[0][0], 0, 0, 0);
            s[0][1] = __builtin_amdgcn_mfma_f32_16x16x32_bf16(kf0, qf[1][ch], s[0][1], 0, 0, 0);
            s[1][0] = __builtin_amdgcn_mfma_f32_16x16x32_bf16(kf1, qf[0][ch], s[1][0], 0, 0, 0);
            s[1][1] = __builtin_amdgcn_mfma_f32_16x16x32_bf16(kf1, qf[1][ch], s[1][1], 0, 0, 0);
        }
        // ---- per-wave partial rowmax (reduce over hi groups) ----
        float pmax[2];
        #pragma unroll
        for (int qt = 0; qt < 2; ++qt) {
            float m0 = fmaxf(fmaxf(s[0][qt][0], s[0][qt][1]), fmaxf(s[0][qt][2], s[0][qt][3]));
            float m1 = fmaxf(fmaxf(s[1][qt][0], s[1][qt][1]), fmaxf(s[1][qt][2], s[1][qt][3]));
            float m = fmaxf(m0, m1);
            m = fmaxf(m, __shfl_xor(m, 16));
            m = fmaxf(m, __shfl_xor(m, 32));
            pmax[qt] = m;
        }
        if (lane < 16) { pm[lo][w] = pmax[0]; pm[16 + lo][w] = pmax[1]; }
        __syncthreads();   // barrier A
        float m_new[2], alpha[2];
        #pragma unroll
        for (int qt = 0; qt < 2; ++qt) {
            float4 pv = *(const float4*)(&pm[16*qt + lo][0]);
            float mi = fmaxf(fmaxf(pv.x, pv.y), fmaxf(pv.z, pv.w));
            m_new[qt] = fmaxf(m_old[qt], mi);
            alpha[qt] = __expf(m_old[qt] - m_new[qt]);
            m_old[qt] = m_new[qt];
        }
        if (w == 0 && lane < 16) { alphaS[lo] = alpha[0]; alphaS[16 + lo] = alpha[1]; }
        // ---- exp, partial sums, write P (packed b64) ----
        float psum[2] = {0.f, 0.f};
        #pragma unroll
        for (int kt = 0; kt < 2; ++kt)
            #pragma unroll
            for (int qt = 0; qt < 2; ++qt) {
                float p0 = __expf(s[kt][qt][0] - m_new[qt]);
                float p1 = __expf(s[kt][qt][1] - m_new[qt]);
                float p2 = __expf(s[kt][qt][2] - m_new[qt]);
                float p3 = __expf(s[kt][qt][3] - m_new[qt]);
                psum[qt] += (p0 + p1) + (p2 + p3);
                unsigned w0 = (unsigned)f2bf(p0) | ((unsigned)f2bf(p1) << 16);
                unsigned w1 = (unsigned)f2bf(p2) | ((unsigned)f2bf(p3) << 16);
                uint2 pk; pk.x = w0; pk.y = w1;
                *(uint2*)(Ps + (16*qt + lo)*PSTR + 32*w + 16*kt + 4*hi) = pk;
            }
        #pragma unroll
        for (int qt = 0; qt < 2; ++qt) {
            psum[qt] += __shfl_xor(psum[qt], 16);
            psum[qt] += __shfl_xor(psum[qt], 32);
        }
        if (lane < 16) { pl[lo][w] = psum[0]; pl[16 + lo][w] = psum[1]; }
        __syncthreads();   // barrier B
        // ---- l update + rescale accumulators ----
        #pragma unroll
        for (int qt = 0; qt < 2; ++qt) {
            float4 plv = *(const float4*)(&pl[16*qt + lo][0]);
            l_run[qt] = l_run[qt] * alpha[qt] + ((plv.x + plv.y) + (plv.z + plv.w));
        }
        #pragma unroll
        for (int qt = 0; qt < 2; ++qt) {
            float4 av = *(const float4*)(alphaS + 16*qt + 4*hi);
            float am[4] = {av.x, av.y, av.z, av.w};
            #pragma unroll
            for (int ct = 0; ct < 2; ++ct)
                #pragma unroll
                for (int r = 0; r < 4; ++r)
                    acc_o[qt][ct][r] *= am[r];
        }
        // ---- PV: A=P from LDS, B=V direct from global ----
        #pragma unroll
        for (int ch = 0; ch < 4; ++ch) {
            bf16x8 pa0 = *(const bf16x8*)(Ps + (0  + lo)*PSTR + 32*ch + 8*hi);
            bf16x8 pa1 = *(const bf16x8*)(Ps + (16 + lo)*PSTR + 32*ch + 8*hi);
            bf16x8 vb0 = *(const bf16x8*)(Vv + (size_t)(32*w + lo)*N_      + j0 + 32*ch + 8*hi);
            bf16x8 vb1 = *(const bf16x8*)(Vv + (size_t)(32*w + 16 + lo)*N_ + j0 + 32*ch + 8*hi);
            acc_o[0][0] = __builtin_amdgcn_mfma_f32_16x16x32_bf16(pa0, vb0, acc_o[0][0], 0, 0, 0);
            acc_o[0][1] = __builtin_amdgcn_mfma_f32_16x16x32_bf16(pa0, vb1, acc_o[0][1], 0, 0, 0);
            acc_o[1][0] = __builtin_amdgcn_mfma_f32_16x16x32_bf16(pa1, vb0, acc_o[1][0], 0, 0, 0);
            acc_o[1][1] = __builtin_amdgcn_mfma_f32_16x16x32_bf16(pa1, vb1, acc_o[1][1], 0, 0, 0);
        }
        // next iter's P writes happen after its barrier A; PV reads above precede it.
    }

    // ---------------- epilogue ----------------
    if (w == 0 && lane < 16) {
        linvS[lo]      = 1.f / l_run[0];
        linvS[16 + lo] = 1.f / l_run[1];
    }
    __syncthreads();   // PV reads done; linv visible
    // att (normalized, bf16) -> Ps[qrow][ch]
    #pragma unroll
    for (int qt = 0; qt < 2; ++qt) {
        float4 lv = *(const float4*)(linvS + 16*qt + 4*hi);
        float lm[4] = {lv.x, lv.y, lv.z, lv.w};
        #pragma unroll
        for (int ct = 0; ct < 2; ++ct)
            #pragma unroll
            for (int r = 0; r < 4; ++r)
                Ps[(16*qt + 4*hi + r)*PSTR + 32*w + 16*ct + lo] =
                    f2bf(acc_o[qt][ct][r] * lm[r]);
    }
    __syncthreads();
    // proj via mfma: A=att (LDS), B=pw bf16 (global)
    f32x4 pr[2][2];
    #pragma unroll
    for (int qt = 0; qt < 2; ++qt)
        #pragma unroll
        for (int ot = 0; ot < 2; ++ot)
            pr[qt][ot] = (f32x4){0.f, 0.f, 0.f, 0.f};
    #pragma unroll
    for (int ch = 0; ch < 4; ++ch) {
        bf16x8 aa0 = *(const bf16x8*)(Ps + (0  + lo)*PSTR + 32*ch + 8*hi);
        bf16x8 aa1 = *(const bf16x8*)(Ps + (16 + lo)*PSTR + 32*ch + 8*hi);
        bf16x8 bw0 = *(const bf16x8*)(pwbf + (size_t)(32*w + lo)*C_      + 32*ch + 8*hi);
        bf16x8 bw1 = *(const bf16x8*)(pwbf + (size_t)(32*w + 16 + lo)*C_ + 32*ch + 8*hi);
        pr[0][0] = __builtin_amdgcn_mfma_f32_16x16x32_bf16(aa0, bw0, pr[0][0], 0, 0, 0);
        pr[0][1] = __builtin_amdgcn_mfma_f32_16x16x32_bf16(aa0, bw1, pr[0][1], 0, 0, 0);
        pr[1][0] = __builtin_amdgcn_mfma_f32_16x16x32_bf16(aa1, bw0, pr[1][0], 0, 0, 0);
        pr[1][1] = __builtin_amdgcn_mfma_f32_16x16x32_bf16(aa1, bw1, pr[1][1], 0, 0, 0);
    }
    // store: out = x + proj + pb
    #pragma unroll
    for (int qt = 0; qt < 2; ++qt)
        #pragma unroll
        for (int ot = 0; ot < 2; ++ot) {
            int o = 32*w + 16*ot + lo;
            float pbv = pb[o];
            size_t base = ((size_t)(b*C_ + o))*N_ + i0 + 16*qt + 4*hi;
            float4 xr = *(const float4*)(x + base);
            float4 res;
            res.x = xr.x + pr[qt][ot][0] + pbv;
            res.y = xr.y + pr[qt][ot][1] + pbv;
            res.z = xr.z + pr[qt][ot][2] + pbv;
            res.w = xr.w + pr[qt][ot][3] + pbv;
            *(float4*)(out + base) = res;
        }
}

extern "C" void kernel_launch(void* const* d_in, const int* in_sizes, int n_in,
                              void* d_out, int out_size, void* d_ws, size_t ws_size,
                              hipStream_t stream) {
    const float* x  = (const float*)d_in[0];
    const float* nw = (const float*)d_in[1];
    const float* nb = (const float*)d_in[2];
    const float* qw = (const float*)d_in[3];
    const float* qb = (const float*)d_in[4];
    const float* pw = (const float*)d_in[5];
    const float* pb = (const float*)d_in[6];
    float* out = (float*)d_out;

    // ws: [stats 64 f][Qt 4MB][Kt 4MB][Vb 4MB][pwbf 32KB]
    float* stats = (float*)d_ws;
    u16* Qt   = (u16*)((char*)d_ws + 256);
    u16* Kt   = Qt + (size_t)B_*N_*C_;
    u16* Vb   = Kt + (size_t)B_*N_*C_;
    u16* pwbf = Vb + (size_t)B_*N_*C_;

    gn_stats_kernel<<<dim3(B_*G_), 256, 0, stream>>>(x, stats);
    cvt_pw_kernel<<<dim3(16), 256, 0, stream>>>(pw, pwbf);
    qkv_gemm_kernel<<<dim3(N_/NT, (3*C_)/OT, B_), 256, 0, stream>>>(
        x, stats, nw, nb, qw, qb, Qt, Kt, Vb);
    attn_kernel<<<dim3(512), 256, 0, stream>>>(Qt, Kt, Vb, pwbf, pb, x, out);
}

// Round 3
// 234.470 us; speedup vs baseline: 4.8173x; 1.1634x over previous
//
#include <hip/hip_runtime.h>

typedef float  f32x4  __attribute__((ext_vector_type(4)));
typedef short  bf16x8 __attribute__((ext_vector_type(8)));
typedef unsigned short u16;

constexpr int B_ = 4;
constexpr int C_ = 128;
constexpr int N_ = 4096;
constexpr int G_ = 8;
constexpr int CperG = 16;
constexpr float EPS_ = 1e-5f;
constexpr float SCALE_ = 0.08838834764831845f;  // 1/sqrt(C)

__device__ inline u16 f2bf(float f) {
    union { float f; unsigned u; } v; v.f = f;
    unsigned r = v.u + 0x7fffu + ((v.u >> 16) & 1u);  // RNE
    return (u16)(r >> 16);
}
__device__ inline unsigned pk2(float a, float b) {
    return (unsigned)f2bf(a) | ((unsigned)f2bf(b) << 16);
}

// ------------- 1. prep: GN partial sums (atomic) + weight bf16 conversion -------------
// blocks 0..255: 8 blocks per (b,g), atomicAdd partial (S, SS) into stats.
// blocks 256..319: convert qkv_w (49152 f32) then proj_w (16384 f32) to bf16.
__global__ __launch_bounds__(256) void prep_kernel(const float* __restrict__ x,
                                                   const float* __restrict__ qw,
                                                   const float* __restrict__ pw,
                                                   float* __restrict__ stats,
                                                   u16* __restrict__ qwbf,
                                                   u16* __restrict__ pwbf) {
    __shared__ float rs[4], rss[4];
    int blk = blockIdx.x;
    if (blk < 256) {
        int bg = blk >> 3, chunk = blk & 7;
        const float4* xp = (const float4*)(x + (size_t)bg * (CperG * N_)) + chunk * 2048;
        float s = 0.f, ss = 0.f;
        for (int i = threadIdx.x; i < 2048; i += 256) {
            float4 v = xp[i];
            s  += v.x + v.y + v.z + v.w;
            ss += v.x*v.x + v.y*v.y + v.z*v.z + v.w*v.w;
        }
        #pragma unroll
        for (int off = 32; off > 0; off >>= 1) {
            s  += __shfl_down(s, off);
            ss += __shfl_down(ss, off);
        }
        int wv = threadIdx.x >> 6, ln = threadIdx.x & 63;
        if (ln == 0) { rs[wv] = s; rss[wv] = ss; }
        __syncthreads();
        if (threadIdx.x == 0) {
            atomicAdd(&stats[bg*2],     rs[0] + rs[1] + rs[2] + rs[3]);
            atomicAdd(&stats[bg*2 + 1], rss[0] + rss[1] + rss[2] + rss[3]);
        }
    } else {
        int fidx = ((blk - 256) * 256 + threadIdx.x) * 4;   // 64 blocks * 1024 f32
        float4 v;
        u16* dst;
        if (fidx < 3*C_*C_) { v = *(const float4*)(qw + fidx); dst = qwbf + fidx; }
        else { int j = fidx - 3*C_*C_; v = *(const float4*)(pw + j); dst = pwbf + j; }
        ushort4 o;
        o.x = f2bf(v.x); o.y = f2bf(v.y); o.z = f2bf(v.z); o.w = f2bf(v.w);
        *(ushort4*)dst = o;
    }
}

// ------------- 2. QKV via MFMA, fused GroupNorm, bf16 outputs -------------
// Qt[b][n][c]=(q+qb)*SCALE, Kt[b][n][c]=k+qb, Vb[b][c][n]=v+qb.
// Block: 64-pixel tile, 4 waves (16 n each). h staged bf16 [n][c] in LDS.
constexpr int HS = 136;   // u16 stride (mult of 8 for aligned b128 reads)

__global__ __launch_bounds__(256) void qkv_kernel(const float* __restrict__ x,
                                                  const float* __restrict__ stats,
                                                  const float* __restrict__ nw,
                                                  const float* __restrict__ nb,
                                                  const u16* __restrict__ qwbf,
                                                  const float* __restrict__ qb,
                                                  u16* __restrict__ Qt,
                                                  u16* __restrict__ Kt,
                                                  u16* __restrict__ Vb) {
    int n0 = (blockIdx.x & 63) * 64;
    int b  = blockIdx.x >> 6;
    __shared__ u16 hs[64 * HS];   // [n][c] bf16, ~17 KB
    int t = threadIdx.x;
    const float invM = 1.f / (float)(CperG * N_);
    #pragma unroll
    for (int r = 0; r < 8; ++r) {
        int idx = t + (r << 8);
        int c = idx >> 4, n4 = idx & 15;
        int g = c >> 4;
        float S = stats[(b*G_ + g)*2], SS = stats[(b*G_ + g)*2 + 1];
        float mean = S * invM;
        float rstd = rsqrtf(SS * invM - mean*mean + EPS_);
        float wgt = nw[c] * rstd;
        float bia = nb[c] - mean * wgt;               // h = x*wgt + bia
        float4 xv = *(const float4*)(x + ((size_t)(b*C_ + c))*N_ + n0 + n4*4);
        int base = (n4*4) * HS + c;
        hs[base         ] = f2bf(xv.x*wgt + bia);
        hs[base +     HS] = f2bf(xv.y*wgt + bia);
        hs[base + 2 * HS] = f2bf(xv.z*wgt + bia);
        hs[base + 3 * HS] = f2bf(xv.w*wgt + bia);
    }
    __syncthreads();
    int w = t >> 6, lane = t & 63, lo = lane & 15, hi = lane >> 4;
    bf16x8 hf[4];
    #pragma unroll
    for (int ch = 0; ch < 4; ++ch)
        hf[ch] = *(const bf16x8*)(hs + (16*w + lo)*HS + 32*ch + 8*hi);

    // Q/K: 16 o-tiles of 16; orientation A=W (m=o), B=h (n=pixel)
    #pragma unroll
    for (int ot = 0; ot < 16; ++ot) {
        int ob = ot * 16;
        f32x4 acc = (f32x4){0.f, 0.f, 0.f, 0.f};
        #pragma unroll
        for (int ch = 0; ch < 4; ++ch) {
            bf16x8 wf = *(const bf16x8*)(qwbf + (size_t)(ob + lo)*C_ + 32*ch + 8*hi);
            acc = __builtin_amdgcn_mfma_f32_16x16x32_bf16(wf, hf[ch], acc, 0, 0, 0);
        }
        float4 bv = *(const float4*)(qb + ob + 4*hi);   // o = ob+4hi+r
        int n = n0 + 16*w + lo;
        ushort4 o4;
        if (ob < C_) {
            o4.x = f2bf((acc[0] + bv.x) * SCALE_);
            o4.y = f2bf((acc[1] + bv.y) * SCALE_);
            o4.z = f2bf((acc[2] + bv.z) * SCALE_);
            o4.w = f2bf((acc[3] + bv.w) * SCALE_);
            *(ushort4*)(Qt + ((size_t)b*N_ + n)*C_ + ob + 4*hi) = o4;
        } else {
            o4.x = f2bf(acc[0] + bv.x);
            o4.y = f2bf(acc[1] + bv.y);
            o4.z = f2bf(acc[2] + bv.z);
            o4.w = f2bf(acc[3] + bv.w);
            *(ushort4*)(Kt + ((size_t)b*N_ + n)*C_ + (ob - C_) + 4*hi) = o4;
        }
    }
    // V: 8 o-tiles; orientation A=h (m=pixel), B=W (n=o)
    #pragma unroll
    for (int ov = 0; ov < 8; ++ov) {
        f32x4 acc = (f32x4){0.f, 0.f, 0.f, 0.f};
        #pragma unroll
        for (int ch = 0; ch < 4; ++ch) {
            bf16x8 wf = *(const bf16x8*)(qwbf + (size_t)(2*C_ + ov*16 + lo)*C_ + 32*ch + 8*hi);
            acc = __builtin_amdgcn_mfma_f32_16x16x32_bf16(hf[ch], wf, acc, 0, 0, 0);
        }
        float bia = qb[2*C_ + ov*16 + lo];              // o = col = lo
        ushort4 o4;
        o4.x = f2bf(acc[0] + bia);
        o4.y = f2bf(acc[1] + bia);
        o4.z = f2bf(acc[2] + bia);
        o4.w = f2bf(acc[3] + bia);                      // 4 consecutive n
        *(ushort4*)(Vb + ((size_t)b*C_ + ov*16 + lo)*N_ + n0 + 16*w + 4*hi) = o4;
    }
}

// ------------- 3. Barrier-free MFMA flash attention + proj + residual -------------
// Block: 32 queries, 4 waves. Wave w owns key stripe [1024w, 1024w+1024),
// private online-softmax state over ALL 128 channels. No in-loop barriers:
// P transform + alpha redistribution are wave-private LDS (same-wave ds order).
// K-frags register-double-buffered one iter ahead. End: 4-way (m,l,O) combine
// (the only barriers), then mfma proj + bias + residual.
constexpr int PS = 40;    // Ps row stride (u16), mult of 8 for aligned b128

__global__ __launch_bounds__(256, 2) void attn_kernel(const u16* __restrict__ Qt,
                                                      const u16* __restrict__ Kt,
                                                      const u16* __restrict__ Vbuf,
                                                      const u16* __restrict__ pwbf,
                                                      const float* __restrict__ pb,
                                                      const float* __restrict__ x,
                                                      float* __restrict__ out) {
    int lb = blockIdx.x;
    int b  = lb & 3;                                   // XCD-swizzle: one batch per XCD-pair
    int i0 = 32 * ((lb >> 3) + ((lb & 4) ? 64 : 0));
    int t = threadIdx.x;
    int w = t >> 6, lane = t & 63, lo = lane & 15, hi = lane >> 4;

    const u16* Qb = Qt   + (size_t)b * N_ * C_;
    const u16* Kw = Kt   + (size_t)b * N_ * C_ + (size_t)(1024*w) * C_;
    const u16* Vv = Vbuf + (size_t)b * C_ * N_;
    const int vcol0 = 1024 * w;

    __shared__ u16 Ps[4 * 32 * PS];                    // wave-private P tiles
    __shared__ float aS[4][32];                        // wave-private alpha bcast
    __shared__ float mW[4][32], lW[4][32], fS[4][32];
    __shared__ float Ob[32 * 132];                     // combined O (f32)
    u16* Psw = Ps + w * 32 * PS;

    // persistent Q B-frags
    bf16x8 qf[2][4];
    #pragma unroll
    for (int qt = 0; qt < 2; ++qt)
        #pragma unroll
        for (int ch = 0; ch < 4; ++ch)
            qf[qt][ch] = *(const bf16x8*)(Qb + (size_t)(i0 + 16*qt + lo)*C_ + 32*ch + 8*hi);

    f32x4 acc_o[2][8];
    #pragma unroll
    for (int qt = 0; qt < 2; ++qt)
        #pragma unroll
        for (int ct = 0; ct < 8; ++ct)
            acc_o[qt][ct] = (f32x4){0.f, 0.f, 0.f, 0.f};
    float m_old[2] = {-3e38f, -3e38f};
    float l_run[2] = {0.f, 0.f};

    // prime K fragments (iter 0)
    bf16x8 kf[2][4], kn[2][4];
    #pragma unroll
    for (int kt = 0; kt < 2; ++kt)
        #pragma unroll
        for (int ch = 0; ch < 4; ++ch)
            kf[kt][ch] = *(const bf16x8*)(Kw + (size_t)(16*kt + lo)*C_ + 32*ch + 8*hi);

    for (int it = 0; it < 32; ++it) {
        // prefetch next iter's K (reads 32 rows past stripe on last iter — in-bounds of ws)
        const u16* Kn = Kw + (size_t)(32*(it + 1)) * C_;
        #pragma unroll
        for (int kt = 0; kt < 2; ++kt)
            #pragma unroll
            for (int ch = 0; ch < 4; ++ch)
                kn[kt][ch] = *(const bf16x8*)(Kn + (size_t)(16*kt + lo)*C_ + 32*ch + 8*hi);
        // V for current iter (consumed at end of iter — latency hidden)
        bf16x8 vb[8];
        #pragma unroll
        for (int ct = 0; ct < 8; ++ct)
            vb[ct] = *(const bf16x8*)(Vv + (size_t)(16*ct + lo)*N_ + vcol0 + 32*it + 8*hi);

        // ---- QK: S^T frags; D rows=key(4hi+r+16kt), cols=query(lo) ----
        f32x4 s[2][2];
        #pragma unroll
        for (int kt = 0; kt < 2; ++kt)
            #pragma unroll
            for (int qt = 0; qt < 2; ++qt)
                s[kt][qt] = (f32x4){0.f, 0.f, 0.f, 0.f};
        #pragma unroll
        for (int ch = 0; ch < 4; ++ch) {
            s[0][0] = __builtin_amdgcn_mfma_f32_16x16x32_bf16(kf[0][ch], qf[0][ch], s[0][0], 0, 0, 0);
            s[0][1] = __builtin_amdgcn_mfma_f32_16x16x32_bf16(kf[0][ch], qf[1][ch], s[0][1], 0, 0, 0);
            s[1][0] = __builtin_amdgcn_mfma_f32_16x16x32_bf16(kf[1][ch], qf[0][ch], s[1][0], 0, 0, 0);
            s[1][1] = __builtin_amdgcn_mfma_f32_16x16x32_bf16(kf[1][ch], qf[1][ch], s[1][1], 0, 0, 0);
        }
        // ---- in-wave online softmax (query = 16qt+lo) ----
        float m_new[2], alpha[2];
        #pragma unroll
        for (int qt = 0; qt < 2; ++qt) {
            float m0 = fmaxf(fmaxf(s[0][qt][0], s[0][qt][1]), fmaxf(s[0][qt][2], s[0][qt][3]));
            float m1 = fmaxf(fmaxf(s[1][qt][0], s[1][qt][1]), fmaxf(s[1][qt][2], s[1][qt][3]));
            float m = fmaxf(m0, m1);
            m = fmaxf(m, __shfl_xor(m, 16));
            m = fmaxf(m, __shfl_xor(m, 32));
            m_new[qt] = fmaxf(m_old[qt], m);
            alpha[qt] = __expf(m_old[qt] - m_new[qt]);
            m_old[qt] = m_new[qt];
        }
        if (lane < 16) { aS[w][lo] = alpha[0]; aS[w][16 + lo] = alpha[1]; }
        float psum[2] = {0.f, 0.f};
        #pragma unroll
        for (int kt = 0; kt < 2; ++kt)
            #pragma unroll
            for (int qt = 0; qt < 2; ++qt) {
                float p0 = __expf(s[kt][qt][0] - m_new[qt]);
                float p1 = __expf(s[kt][qt][1] - m_new[qt]);
                float p2 = __expf(s[kt][qt][2] - m_new[qt]);
                float p3 = __expf(s[kt][qt][3] - m_new[qt]);
                psum[qt] += (p0 + p1) + (p2 + p3);
                uint2 pkd; pkd.x = pk2(p0, p1); pkd.y = pk2(p2, p3);
                *(uint2*)(Psw + (16*qt + lo)*PS + 16*kt + 4*hi) = pkd;
            }
        #pragma unroll
        for (int qt = 0; qt < 2; ++qt) {
            psum[qt] += __shfl_xor(psum[qt], 16);
            psum[qt] += __shfl_xor(psum[qt], 32);
            l_run[qt] = l_run[qt] * alpha[qt] + psum[qt];
        }
        // alpha at accumulator rows (q = 16qt+4hi+r) via wave-private LDS
        float4 a0 = *(const float4*)(&aS[w][4*hi]);
        float4 a1 = *(const float4*)(&aS[w][16 + 4*hi]);
        float am0[4] = {a0.x, a0.y, a0.z, a0.w};
        float am1[4] = {a1.x, a1.y, a1.z, a1.w};
        #pragma unroll
        for (int ct = 0; ct < 8; ++ct)
            #pragma unroll
            for (int r = 0; r < 4; ++r) {
                acc_o[0][ct][r] *= am0[r];
                acc_o[1][ct][r] *= am1[r];
            }
        // ---- PV: A = P (wave-private LDS), B = V (regs) ----
        bf16x8 pa0 = *(const bf16x8*)(Psw + (size_t)lo * PS + 8*hi);
        bf16x8 pa1 = *(const bf16x8*)(Psw + (size_t)(16 + lo) * PS + 8*hi);
        #pragma unroll
        for (int ct = 0; ct < 8; ++ct) {
            acc_o[0][ct] = __builtin_amdgcn_mfma_f32_16x16x32_bf16(pa0, vb[ct], acc_o[0][ct], 0, 0, 0);
            acc_o[1][ct] = __builtin_amdgcn_mfma_f32_16x16x32_bf16(pa1, vb[ct], acc_o[1][ct], 0, 0, 0);
        }
        // rotate K buffers
        #pragma unroll
        for (int kt = 0; kt < 2; ++kt)
            #pragma unroll
            for (int ch = 0; ch < 4; ++ch)
                kf[kt][ch] = kn[kt][ch];
    }

    // ---------------- combine 4 wave-partials ----------------
    if (lane < 16) {
        mW[w][lo] = m_old[0]; mW[w][16 + lo] = m_old[1];
        lW[w][lo] = l_run[0]; lW[w][16 + lo] = l_run[1];
    }
    __syncthreads();
    float fac[2];
    #pragma unroll
    for (int qt = 0; qt < 2; ++qt) {
        int q = 16*qt + lo;
        float m0 = mW[0][q], m1 = mW[1][q], m2 = mW[2][q], m3 = mW[3][q];
        float mt = fmaxf(fmaxf(m0, m1), fmaxf(m2, m3));
        float lt = lW[0][q]*__expf(m0 - mt) + lW[1][q]*__expf(m1 - mt)
                 + lW[2][q]*__expf(m2 - mt) + lW[3][q]*__expf(m3 - mt);
        fac[qt] = __expf(m_old[qt] - mt) / lt;
    }
    if (lane < 16) { fS[w][lo] = fac[0]; fS[w][16 + lo] = fac[1]; }
    float4 f0 = *(const float4*)(&fS[w][4*hi]);
    float4 f1 = *(const float4*)(&fS[w][16 + 4*hi]);
    float fm0[4] = {f0.x, f0.y, f0.z, f0.w};
    float fm1[4] = {f1.x, f1.y, f1.z, f1.w};
    #pragma unroll
    for (int ct = 0; ct < 8; ++ct)
        #pragma unroll
        for (int r = 0; r < 4; ++r) {
            acc_o[0][ct][r] *= fm0[r];
            acc_o[1][ct][r] *= fm1[r];
        }
    // sequential accumulate into Ob[q][c]
    for (int ww = 0; ww < 4; ++ww) {
        if (w == ww) {
            #pragma unroll
            for (int qt = 0; qt < 2; ++qt)
                #pragma unroll
                for (int ct = 0; ct < 8; ++ct)
                    #pragma unroll
                    for (int r = 0; r < 4; ++r) {
                        int q = 16*qt + 4*hi + r, c = 16*ct + lo;
                        if (ww == 0) Ob[q*132 + c]  = acc_o[qt][ct][r];
                        else         Ob[q*132 + c] += acc_o[qt][ct][r];
                    }
        }
        __syncthreads();
    }
    // ---------------- proj (wave w -> output channels 32w..32w+32) ----------------
    bf16x8 aa[2][4];
    #pragma unroll
    for (int qt = 0; qt < 2; ++qt)
        #pragma unroll
        for (int ch = 0; ch < 4; ++ch) {
            float4 u = *(const float4*)(Ob + (16*qt + lo)*132 + 32*ch + 8*hi);
            float4 v = *(const float4*)(Ob + (16*qt + lo)*132 + 32*ch + 8*hi + 4);
            union { bf16x8 h; unsigned u[4]; } pkd;
            pkd.u[0] = pk2(u.x, u.y); pkd.u[1] = pk2(u.z, u.w);
            pkd.u[2] = pk2(v.x, v.y); pkd.u[3] = pk2(v.z, v.w);
            aa[qt][ch] = pkd.h;
        }
    #pragma unroll
    for (int ot = 0; ot < 2; ++ot) {
        f32x4 pr0 = (f32x4){0.f,0.f,0.f,0.f}, pr1 = (f32x4){0.f,0.f,0.f,0.f};
        int obase = 32*w + 16*ot;
        #pragma unroll
        for (int ch = 0; ch < 4; ++ch) {
            bf16x8 bw = *(const bf16x8*)(pwbf + (size_t)(obase + lo)*C_ + 32*ch + 8*hi);
            pr0 = __builtin_amdgcn_mfma_f32_16x16x32_bf16(aa[0][ch], bw, pr0, 0, 0, 0);
            pr1 = __builtin_amdgcn_mfma_f32_16x16x32_bf16(aa[1][ch], bw, pr1, 0, 0, 0);
        }
        int o = obase + lo;
        float pbv = pb[o];
        #pragma unroll
        for (int qt = 0; qt < 2; ++qt) {
            f32x4 pr = qt ? pr1 : pr0;
            size_t base = ((size_t)(b*C_ + o))*N_ + i0 + 16*qt + 4*hi;
            float4 xr = *(const float4*)(x + base);
            float4 res;
            res.x = xr.x + pr[0] + pbv;
            res.y = xr.y + pr[1] + pbv;
            res.z = xr.z + pr[2] + pbv;
            res.w = xr.w + pr[3] + pbv;
            *(float4*)(out + base) = res;
        }
    }
}

extern "C" void kernel_launch(void* const* d_in, const int* in_sizes, int n_in,
                              void* d_out, int out_size, void* d_ws, size_t ws_size,
                              hipStream_t stream) {
    const float* x  = (const float*)d_in[0];
    const float* nw = (const float*)d_in[1];
    const float* nb = (const float*)d_in[2];
    const float* qw = (const float*)d_in[3];
    const float* qb = (const float*)d_in[4];
    const float* pw = (const float*)d_in[5];
    const float* pb = (const float*)d_in[6];
    float* out = (float*)d_out;

    // ws: [stats 256B][Qt 4MB][Kt 4MB][Vb 4MB][qwbf 96KB][pwbf 32KB]
    float* stats = (float*)d_ws;
    u16* Qt   = (u16*)((char*)d_ws + 256);
    u16* Kt   = Qt + (size_t)B_*N_*C_;
    u16* Vb   = Kt + (size_t)B_*N_*C_;
    u16* qwbf = Vb + (size_t)B_*N_*C_;
    u16* pwbf = qwbf + 3*C_*C_;

    hipMemsetAsync(stats, 0, 64 * sizeof(float), stream);
    prep_kernel<<<dim3(320), 256, 0, stream>>>(x, qw, pw, stats, qwbf, pwbf);
    qkv_kernel<<<dim3(256), 256, 0, stream>>>(x, stats, nw, nb, qwbf, qb, Qt, Kt, Vb);
    attn_kernel<<<dim3(512), 256, 0, stream>>>(Qt, Kt, Vb, pwbf, pb, x, out);
}